// Round 5
// baseline (256.499 us; speedup 1.0000x reference)
//
#include <hip/hip_runtime.h>

// H2GCNConv: out[:, 0:128]   = segment_sum(w1 * x[col1], row1)
//            out[:, 128:256] = segment_sum(w2 * x[col2], row2)
// N = 50000, d = 128, out stride = 256 floats.
//
// Round 11: rounds 1/2 measured LDS atomics at ~200 cy per wave-op,
// CU-serialized, REGARDLESS of type (CAS fp == native ds_add_f32 == slow;
// 1860us ~= 1870us). That tax explains bin_scatter's stubborn ~100us (288
// atomic instrs/WG) and bucket_accum's crow/rank atomics. This round removes
// every hot-path LDS atomic via wave ballot-match (match-any: 10 ballots ->
// same-bin mask -> rank/leader; leader does plain LDS RMW on a WAVE-PRIVATE
// histogram/cursor). bucket_accum: wave-cooperative segment loads + 6-bit
// row-match routes records into per-(wave,row) cells; row-sort deleted;
// phase B concatenates cells -> round-6 register gather loop.
// Pipeline: cvt_bf16 -> bin_scatter -> bucket_accum.

#define N_NODES 50000
#define D 128
#define OUT_STRIDE 256

#define BSHIFT 6                       // 64 rows / bucket
#define BROWS 64
#define NBUCK ((N_NODES + BROWS - 1) >> BSHIFT)   // 782
#define BBITS 10                       // 782 < 1024
#define CHUNK 9216                     // edges per bin_scatter WG
#define WSEG (CHUNK / 8)               // 1152 records per wave
#define CELLCAP 16                     // per-(wave,row) cell (lambda<=4, +huge margin)
#define RSCR 96                        // per-wave row scratch
#define SPILLCAP 128                   // per-WG overflow list

typedef float vf2 __attribute__((ext_vector_type(2)));

static inline size_t align256(size_t x) { return (x + 255) & ~(size_t)255; }

__device__ __forceinline__ unsigned f32_to_bf16_bits(float f) {
    unsigned u = __float_as_uint(f);
    return (u + 0x7fffu + ((u >> 16) & 1u)) >> 16;   // RNE
}

// match-any over BITS-bit value v across the wave; returns mask of lanes with
// equal v (valid lanes only).
template<int BITS>
__device__ __forceinline__ unsigned long long wave_match(int v, bool valid) {
    unsigned long long m = __ballot(valid ? 1 : 0);
    #pragma unroll
    for (int k = 0; k < BITS; ++k) {
        unsigned long long vb = __ballot((v >> k) & 1);
        m &= ((v >> k) & 1) ? vb : ~vb;
    }
    return m;
}

// ---------------- 1. binned scatter: chunk -> bin-sorted contiguous block --
// Per-wave histograms + cursors (hwc[w][bin], no atomics). ends are written
// bucket-major (ends[b*ncht + cid]) so bucket_accum reads them coalesced.

__global__ void __launch_bounds__(512) bin_scatter(
        const int* __restrict__ ei1, const float* __restrict__ w1, int E1, int nch1,
        const int* __restrict__ ei2, const float* __restrict__ w2, int E2,
        uint2* __restrict__ inter, int* __restrict__ ends, int ncht) {
    int cid = blockIdx.x;
    int g = (cid < nch1) ? 0 : 1;
    int chunk = g ? cid - nch1 : cid;
    const int*   ei = g ? ei2 : ei1;
    const float* w  = g ? w2  : w1;
    int E           = g ? E2  : E1;
    int e0  = chunk * CHUNK;
    int cnt = min(CHUNK, E - e0);

    __shared__ uint2 stage[CHUNK];              // 72 KB
    __shared__ int hwc[8][NBUCK];               // 25 KB: per-wave hist -> cursors
    __shared__ int wsum[8];
    int t = threadIdx.x, lane = t & 63, wid = t >> 6;
    unsigned long long below = (1ull << lane) - 1ull;
    for (int i = t; i < 8 * NBUCK; i += 512) ((int*)hwc)[i] = 0;
    __syncthreads();

    int s0 = wid * WSEG, s1 = min(cnt, s0 + WSEG);
    // pass 1: per-wave histogram via ballot-match (no atomics)
    for (int i0 = s0; i0 < s1; i0 += 64) {
        int i = i0 + lane;
        bool v = (i < s1);
        int row = v ? ei[e0 + i] : 0;
        int bb = row >> BSHIFT;
        unsigned long long m = wave_match<BBITS>(bb, v);
        if (v && (m & below) == 0)                 // leader of its bin-group
            hwc[wid][bb] += __popcll(m);           // wave-private: plain RMW
    }
    __syncthreads();
    // scan: per bin, per-wave prefix + cross-bin exclusive scan; write ends
    {
        int b0 = 2 * t, b1 = 2 * t + 1;
        int h0[8], h1[8];
        int t0 = 0, t1 = 0;
        if (b0 < NBUCK) {
            #pragma unroll
            for (int q = 0; q < 8; ++q) { h0[q] = hwc[q][b0]; t0 += h0[q]; }
        }
        if (b1 < NBUCK) {
            #pragma unroll
            for (int q = 0; q < 8; ++q) { h1[q] = hwc[q][b1]; t1 += h1[q]; }
        }
        int p = t0 + t1, s = p;
        #pragma unroll
        for (int d2 = 1; d2 < 64; d2 <<= 1) { int u = __shfl_up(s, d2, 64); if (lane >= d2) s += u; }
        if (lane == 63) wsum[wid] = s;
        __syncthreads();
        int add = 0;
        #pragma unroll
        for (int k = 0; k < 8; ++k) if (k < wid) add += wsum[k];
        s += add;
        int excl = s - p;
        if (b0 < NBUCK) {
            int a = excl;
            #pragma unroll
            for (int q = 0; q < 8; ++q) { hwc[q][b0] = a; a += h0[q]; }
            ends[(size_t)b0 * ncht + cid] = a;     // inclusive chunk-local end
        }
        if (b1 < NBUCK) {
            int a = excl + t0;
            #pragma unroll
            for (int q = 0; q < 8; ++q) { hwc[q][b1] = a; a += h1[q]; }
            ends[(size_t)b1 * ncht + cid] = a;
        }
    }
    __syncthreads();
    // pass 2: re-match + per-wave cursor + scatter into stage (no atomics)
    for (int i0 = s0; i0 < s1; i0 += 64) {
        int i = i0 + lane;
        bool v = (i < s1);
        int row = v ? ei[e0 + i] : 0;
        int col = v ? ei[E + e0 + i] : 0;
        float wv = v ? w[e0 + i] : 0.f;
        int bb = row >> BSHIFT;
        unsigned long long m = wave_match<BBITS>(bb, v);
        if (v) {
            int rank = __popcll(m & below);
            int base = hwc[wid][bb];               // matched lanes: broadcast read
            stage[base + rank] = make_uint2((unsigned)(row & (BROWS - 1)),
                                            (unsigned)col | (f32_to_bf16_bits(wv) << 16));
            if (rank == 0) hwc[wid][bb] = base + __popcll(m);
        }
    }
    __syncthreads();
    // flush coalesced
    for (int i = t; i < cnt; i += 512)
        inter[(size_t)cid * CHUNK + i] = stage[i];
}

// ---------------- 2. x -> bf16x2 pack --------------------------------------

__global__ void cvt_bf16(const float* __restrict__ x, uint2* __restrict__ xb4, int n4) {
    int i = blockIdx.x * blockDim.x + threadIdx.x;
    if (i >= n4) return;
    float4 v = ((const float4*)x)[i];
    unsigned a = f32_to_bf16_bits(v.x);
    unsigned b = f32_to_bf16_bits(v.y);
    unsigned c = f32_to_bf16_bits(v.z);
    unsigned d = f32_to_bf16_bits(v.w);
    xb4[i] = make_uint2(a | (b << 16), c | (d << 16));
}

// ---------------- 3. bucket accum: match-route + register gather -----------
// One WG per (bucket, graph). Phase A: wave w pulls chunk-segments w, w+8,...
// wave-cooperatively; 6-bit row ballot-match routes each record into its
// per-(wave,row) cell (plain LDS writes; overflow -> tiny spill list).
// Phase B: wave w owns rows [w*8, w*8+8): concatenate the row's 8 cells into
// wave scratch, then the round-6 4-deep register gather loop. No row sort,
// no hot-path atomics.

__device__ __forceinline__ void fma_rec(unsigned p, unsigned rec, float& ax, float& ay) {
    float w = __int_as_float((int)(rec & 0xffff0000u));   // bf16 bits already high
    ax += w * __int_as_float((int)(p << 16));
    ay += w * __int_as_float((int)(p & 0xffff0000u));
}

__global__ void __launch_bounds__(512, 4) bucket_accum(
        const uint2* __restrict__ inter, const int* __restrict__ ends,
        const unsigned* __restrict__ xb,   // [N,64] bf16x2
        float* __restrict__ out, int nch1, int nch2, int ncht) {
    int b = blockIdx.x, g = blockIdx.y;
    int c0 = g ? nch1 : 0;
    int nc = g ? nch2 : nch1;

    __shared__ unsigned region[8][BROWS][CELLCAP];   // 32 KB
    __shared__ int cwi[8][BROWS];                    // 2 KB logical cell counts
    __shared__ uint2 spill[SPILLCAP];                // 1 KB
    __shared__ int sp_cnt;
    __shared__ unsigned scratch[8][RSCR];            // 3 KB

    int t = threadIdx.x, lane = t & 63, wid = t >> 6;
    unsigned long long below = (1ull << lane) - 1ull;
    for (int i = t; i < 8 * BROWS; i += 512) ((int*)cwi)[i] = 0;
    if (t == 0) sp_cnt = 0;
    __syncthreads();

    // preload this bucket's (and previous bucket's) ends rows: coalesced
    const int* eb  = ends + (size_t)b * ncht + c0;
    const int* ebp = eb - ncht;
    int er0, er1, er2, sr0, sr1, sr2;
    { int ci = lane;       bool v = ci < nc; er0 = v ? eb[ci] : 0; sr0 = (v && b) ? ebp[ci] : 0; }
    { int ci = lane + 64;  bool v = ci < nc; er1 = v ? eb[ci] : 0; sr1 = (v && b) ? ebp[ci] : 0; }
    { int ci = lane + 128; bool v = ci < nc; er2 = v ? eb[ci] : 0; sr2 = (v && b) ? ebp[ci] : 0; }

    // phase A: wave-cooperative segment pull + row match-route
    for (int ci = wid; ci < nc; ci += 8) {
        int slot = ci >> 6, sl = ci & 63;
        int ev = (slot == 0) ? er0 : (slot == 1) ? er1 : er2;
        int svv = (slot == 0) ? sr0 : (slot == 1) ? sr1 : sr2;
        int segs = __shfl(svv, sl, 64);
        int sege = __shfl(ev, sl, 64);
        int segn = sege - segs;
        const uint2* src = inter + (size_t)(c0 + ci) * CHUNK + segs;
        for (int k0 = 0; k0 < segn; k0 += 64) {
            int k = k0 + lane;
            bool v = (k < segn);
            uint2 r = v ? src[k] : make_uint2(0u, 0u);
            int row = (int)(r.x & 63u);
            unsigned long long m = wave_match<6>(row, v);
            if (v) {
                int rank = __popcll(m & below);
                int base = cwi[wid][row];
                int pos = base + rank;
                if (pos < CELLCAP) {
                    region[wid][row][pos] = r.y;
                } else {                       // astronomically rare
                    int sp = atomicAdd(&sp_cnt, 1);
                    if (sp < SPILLCAP) spill[sp] = make_uint2((unsigned)row, r.y);
                }
                if (rank == 0) cwi[wid][row] = base + __popcll(m);
            }
        }
    }
    __syncthreads();
    int spn = min(sp_cnt, SPILLCAP);

    // phase B: each wave accumulates its 8 rows
    for (int r8 = 0; r8 < 8; ++r8) {
        int row = wid * 8 + r8;
        int grow = (b << BSHIFT) + row;
        if (grow >= N_NODES) break;
        int cw[8];
        int tot = 0;
        #pragma unroll
        for (int q = 0; q < 8; ++q) { cw[q] = min(cwi[q][row], CELLCAP); tot += cw[q]; }
        int tt = min(tot, RSCR);
        if (lane < tt) {
            int off = lane, w8 = 0;
            #pragma unroll
            for (int q = 0; q < 7; ++q)
                if (w8 == q && off >= cw[q]) { off -= cw[q]; w8 = q + 1; }
            scratch[wid][lane] = region[w8][row][off];
        }
        int tt2 = tt;
        for (int s2 = 0; s2 < spn; ++s2) {       // spn ~ 0 in practice
            uint2 sv2 = spill[s2];
            if ((int)sv2.x == row && tt2 < RSCR) {
                if (lane == 0) scratch[wid][tt2] = sv2.y;
                ++tt2;
            }
        }
        float ax = 0.f, ay = 0.f;
        int j = 0;
        for (; j + 4 <= tt2; j += 4) {
            unsigned c0r = scratch[wid][j];
            unsigned c1r = scratch[wid][j + 1];
            unsigned c2r = scratch[wid][j + 2];
            unsigned c3r = scratch[wid][j + 3];
            unsigned p0 = xb[(size_t)(c0r & 0xffffu) * 64 + lane];
            unsigned p1 = xb[(size_t)(c1r & 0xffffu) * 64 + lane];
            unsigned p2 = xb[(size_t)(c2r & 0xffffu) * 64 + lane];
            unsigned p3 = xb[(size_t)(c3r & 0xffffu) * 64 + lane];
            fma_rec(p0, c0r, ax, ay);
            fma_rec(p1, c1r, ax, ay);
            fma_rec(p2, c2r, ax, ay);
            fma_rec(p3, c3r, ax, ay);
        }
        for (; j < tt2; ++j) {
            unsigned cr = scratch[wid][j];
            unsigned p = xb[(size_t)(cr & 0xffffu) * 64 + lane];
            fma_rec(p, cr, ax, ay);
        }
        vf2 rv; rv.x = ax; rv.y = ay;
        vf2* o = (vf2*)(out + (size_t)grow * OUT_STRIDE + g * D);
        __builtin_nontemporal_store(rv, o + lane);
    }
}

// ---------------- atomic scatter (fallback if ws too small) ----------------

__global__ void spmm_scatter(const float* __restrict__ x,
                             const int* __restrict__ ei,
                             const float* __restrict__ w,
                             float* __restrict__ out,
                             int E, int col_off) {
    long long gid = (long long)blockIdx.x * blockDim.x + threadIdx.x;
    int e    = (int)(gid >> 5);
    int lane = (int)(gid & 31);
    if (e >= E) return;
    int row  = ei[e];
    int col  = ei[E + e];
    float wv = w[e];
    const float4* xv = (const float4*)(x + (size_t)col * D);
    float4 v = xv[lane];
    float* o = out + (size_t)row * OUT_STRIDE + col_off + lane * 4;
    atomicAdd(o + 0, wv * v.x);
    atomicAdd(o + 1, wv * v.y);
    atomicAdd(o + 2, wv * v.z);
    atomicAdd(o + 3, wv * v.w);
}

extern "C" void kernel_launch(void* const* d_in, const int* in_sizes, int n_in,
                              void* d_out, int out_size, void* d_ws, size_t ws_size,
                              hipStream_t stream) {
    const float* x   = (const float*)d_in[0];
    const int*   ei1 = (const int*)d_in[1];
    const float* w1  = (const float*)d_in[2];
    const int*   ei2 = (const int*)d_in[3];
    const float* w2  = (const float*)d_in[4];
    float* out = (float*)d_out;

    const int E1 = in_sizes[1] / 2;   // 800000
    const int E2 = in_sizes[3] / 2;   // 1600000
    const int block = 256;

    int nch1 = (E1 + CHUNK - 1) / CHUNK;   // 87
    int nch2 = (E2 + CHUNK - 1) / CHUNK;   // 174
    int ncht = nch1 + nch2;                // 261

    // Workspace: ends (bucket-major) | inter (chunk-major) | xb
    size_t ends_b  = align256((size_t)NBUCK * ncht * sizeof(int));
    size_t inter_b = align256((size_t)ncht * CHUNK * sizeof(uint2));
    size_t xb_b    = align256((size_t)N_NODES * 64 * sizeof(unsigned));
    size_t o_ends  = 0;
    size_t o_int   = o_ends + ends_b;
    size_t o_xb    = o_int + inter_b;
    size_t needed  = o_xb + xb_b;

    if (ws_size < needed) {
        // Fallback: atomic scatter (round-0).
        (void)hipMemsetAsync(d_out, 0, (size_t)out_size * sizeof(float), stream);
        long long th1 = (long long)E1 * 32;
        spmm_scatter<<<(int)((th1 + block - 1) / block), block, 0, stream>>>(
            x, ei1, w1, out, E1, 0);
        long long th2 = (long long)E2 * 32;
        spmm_scatter<<<(int)((th2 + block - 1) / block), block, 0, stream>>>(
            x, ei2, w2, out, E2, D);
        return;
    }

    char* ws = (char*)d_ws;
    int*      ends  = (int*)(ws + o_ends);
    uint2*    inter = (uint2*)(ws + o_int);
    unsigned* xb    = (unsigned*)(ws + o_xb);

    // 1. pack x to bf16x2
    {
        int n4 = N_NODES * 32;
        cvt_bf16<<<(n4 + block - 1) / block, block, 0, stream>>>(
            x, (uint2*)xb, n4);
    }

    // 2. atomic-free bin-sort per chunk, coalesced contiguous writes
    bin_scatter<<<ncht, 512, 0, stream>>>(
        ei1, w1, E1, nch1, ei2, w2, E2, inter, ends, ncht);

    // 3. match-route + register-accumulate gather
    {
        dim3 gr(NBUCK, 2);
        bucket_accum<<<gr, 512, 0, stream>>>(inter, ends, xb, out, nch1, nch2, ncht);
    }
}

// Round 6
// 212.932 us; speedup vs baseline: 1.2046x; 1.2046x over previous
//
#include <hip/hip_runtime.h>

// H2GCNConv: out[:, 0:128]   = segment_sum(w1 * x[col1], row1)
//            out[:, 128:256] = segment_sum(w2 * x[col2], row2)
// N = 50000, d = 128, out stride = 256 floats.
//
// Round 12: model: LDS ATOMIC wave-ops ~200cy serialized at the CU DS pipe
// (r1/r2: CAS == native ds_add_f32 == 1870us). Round-4 scatter issued 288
// atomic wave-instrs/WG -> ~50-90us wall = the stubborn residual. Round-5's
// ballot fix failed on occupancy (97KB LDS -> 1 WG/CU) + double matching.
// This round: scatter uses ballot-match ONCE, caches (bin|rowlocal|pos) +
// packed record in registers; pass 2 = one plain u16 LDS read + store. u16
// per-wave hists (12.5KB) + CHUNK 8192 stage (64KB) -> 2 WG/CU. Zero LDS
// atomics in scatter. cvt_bf16 fused into the same launch as extra blocks.
// bucket_accum = round-4 verbatim (proven 97us).
// Pipeline: prep(scatter+cvt roles) -> bucket_accum.

#define N_NODES 50000
#define D 128
#define OUT_STRIDE 256

#define BSHIFT 6                       // 64 rows / bucket
#define BROWS 64
#define NBUCK ((N_NODES + BROWS - 1) >> BSHIFT)   // 782
#define BBITS 10                       // 782 < 1024
#define CHUNK 8192                     // edges per scatter WG (64 KB stage)
#define WSEG (CHUNK / 8)               // 1024 records per wave
#define SITERS (WSEG / 64)             // 16 iterations per wave
#define CAPB 3072                      // per-bucket LDS cap (g2 mean 2046, +22 sigma)

typedef float vf2 __attribute__((ext_vector_type(2)));

static inline size_t align256(size_t x) { return (x + 255) & ~(size_t)255; }

__device__ __forceinline__ unsigned f32_to_bf16_bits(float f) {
    unsigned u = __float_as_uint(f);
    return (u + 0x7fffu + ((u >> 16) & 1u)) >> 16;   // RNE
}

// match-any over BITS-bit value v across the wave; mask of lanes with equal v
// (valid lanes only).
template<int BITS>
__device__ __forceinline__ unsigned long long wave_match(int v, bool valid) {
    unsigned long long m = __ballot(valid ? 1 : 0);
    #pragma unroll
    for (int k = 0; k < BITS; ++k) {
        unsigned long long vb = __ballot((v >> k) & 1);
        m &= ((v >> k) & 1) ? vb : ~vb;
    }
    return m;
}

// ---------------- 1. prep: [0,ncht) scatter role | [ncht,..) cvt role ------
// Scatter: chunk -> bin-sorted contiguous block, atomic-free.
//   pass 1: load edges, ballot-match bin, update WAVE-PRIVATE u16 hist with
//           plain LDS ops (leader only), cache (bin|rowlocal|pos)+rec in regs
//   scan:   782 bins x 8 waves -> per-wave bases (u16, in place) + ends
//   pass 2: stage[base + cached pos] = rec   (no matching, no atomics)
//   flush:  coalesced contiguous write to inter[cid*CHUNK ..]

__global__ void __launch_bounds__(512, 4) prep(
        const int* __restrict__ ei1, const float* __restrict__ w1, int E1, int nch1,
        const int* __restrict__ ei2, const float* __restrict__ w2, int E2, int ncht,
        uint2* __restrict__ inter, int* __restrict__ ends,
        const float* __restrict__ x, uint2* __restrict__ xb4, int n4) {
    int bid = blockIdx.x;
    if (bid >= ncht) {                 // ---- cvt role: x -> bf16x2 pack ----
        int i = (bid - ncht) * 512 + threadIdx.x;
        if (i < n4) {
            float4 v = ((const float4*)x)[i];
            unsigned a = f32_to_bf16_bits(v.x);
            unsigned b = f32_to_bf16_bits(v.y);
            unsigned c = f32_to_bf16_bits(v.z);
            unsigned d = f32_to_bf16_bits(v.w);
            xb4[i] = make_uint2(a | (b << 16), c | (d << 16));
        }
        return;
    }
    // ---- scatter role ----
    int cid = bid;
    int g = (cid < nch1) ? 0 : 1;
    int chunk = g ? cid - nch1 : cid;
    const int*   ei = g ? ei2 : ei1;
    const float* w  = g ? w2  : w1;
    int E           = g ? E2  : E1;
    int e0  = chunk * CHUNK;
    int cnt = min(CHUNK, E - e0);

    __shared__ uint2 stage[CHUNK];                 // 64 KB
    __shared__ unsigned short hwc[8][NBUCK];       // 12.5 KB per-wave hist->base
    __shared__ int wsum[8];
    int t = threadIdx.x, lane = t & 63, wid = t >> 6;
    unsigned long long below = (1ull << lane) - 1ull;
    for (int i = t; i < (8 * NBUCK) / 2; i += 512) ((int*)hwc)[i] = 0;
    __syncthreads();

    int s0 = wid * WSEG, s1 = min(cnt, s0 + WSEG);
    unsigned meta[SITERS];     // bin(10) | rowlocal(6)<<10 | pos(16)<<16
    unsigned recs[SITERS];     // col | bf16(w)<<16
    // pass 1: load + match + cache (no atomics; hist is wave-private)
    #pragma unroll
    for (int k = 0; k < SITERS; ++k) {
        int i = s0 + k * 64 + lane;
        bool v = (i < s1);
        int row = v ? ei[e0 + i] : 0;
        int col = v ? ei[E + e0 + i] : 0;
        float wv = v ? w[e0 + i] : 0.f;
        int bb = row >> BSHIFT;
        unsigned long long m = wave_match<BBITS>(bb, v);
        unsigned rank = (unsigned)__popcll(m & below);
        unsigned base = hwc[wid][bb];              // plain ds_read_u16
        if (v && (m & below) == 0)                 // leader of its bin-group
            hwc[wid][bb] = (unsigned short)(base + (unsigned)__popcll(m));
        meta[k] = (unsigned)bb | ((unsigned)(row & 63) << 10) | ((base + rank) << 16);
        recs[k] = (unsigned)col | (f32_to_bf16_bits(wv) << 16);
    }
    __syncthreads();
    // scan: per-bin totals across waves -> chunk-local bases; write ends
    {
        int b0 = 2 * t, b1 = b0 + 1;
        int h0[8], h1[8];
        int t0 = 0, t1 = 0;
        if (b0 < NBUCK) {
            #pragma unroll
            for (int q = 0; q < 8; ++q) { h0[q] = hwc[q][b0]; t0 += h0[q]; }
        }
        if (b1 < NBUCK) {
            #pragma unroll
            for (int q = 0; q < 8; ++q) { h1[q] = hwc[q][b1]; t1 += h1[q]; }
        }
        int p = t0 + t1, s = p;
        #pragma unroll
        for (int d2 = 1; d2 < 64; d2 <<= 1) { int u = __shfl_up(s, d2, 64); if (lane >= d2) s += u; }
        if (lane == 63) wsum[wid] = s;
        __syncthreads();
        int add = 0;
        #pragma unroll
        for (int k = 0; k < 8; ++k) if (k < wid) add += wsum[k];
        s += add;
        int excl = s - p;
        if (b0 < NBUCK) {
            int a = excl;
            #pragma unroll
            for (int q = 0; q < 8; ++q) { int h = h0[q]; hwc[q][b0] = (unsigned short)a; a += h; }
            ends[(size_t)cid * NBUCK + b0] = a;    // inclusive chunk-local end
        }
        if (b1 < NBUCK) {
            int a = excl + t0;
            #pragma unroll
            for (int q = 0; q < 8; ++q) { int h = h1[q]; hwc[q][b1] = (unsigned short)a; a += h; }
            ends[(size_t)cid * NBUCK + b1] = a;
        }
    }
    __syncthreads();
    // pass 2: place cached records (one plain u16 read, no matching)
    #pragma unroll
    for (int k = 0; k < SITERS; ++k) {
        int i = s0 + k * 64 + lane;
        if (i < s1) {
            unsigned mk = meta[k];
            unsigned bb = mk & 1023u;
            unsigned rlv = (mk >> 10) & 63u;
            unsigned pos = mk >> 16;
            unsigned base = hwc[wid][bb];
            stage[base + pos] = make_uint2(rlv, recs[k]);
        }
    }
    __syncthreads();
    // flush coalesced
    for (int i = t; i < cnt; i += 512)
        inter[(size_t)cid * CHUNK + i] = stage[i];
}

// ---------------- 2. bucket accum (round-4 verbatim, proven 97us) ----------
// One WG per (bucket, graph). Phase A collects the bucket's records from all
// chunks' segments into LDS; counts rows; scan + rank-scatter groups by row;
// each wave register-accumulates 8 rows (round-6 spmm inner loop).

__device__ __forceinline__ void fma_rec(unsigned p, unsigned rec, float& ax, float& ay) {
    float w = __int_as_float((int)(rec & 0xffff0000u));   // bf16 bits already high
    ax += w * __int_as_float((int)(p << 16));
    ay += w * __int_as_float((int)(p & 0xffff0000u));
}

__global__ void __launch_bounds__(512, 4) bucket_accum(
        const uint2* __restrict__ inter, const int* __restrict__ ends,
        const unsigned* __restrict__ xb,   // [N,64] bf16x2
        float* __restrict__ out, int nch1, int nch2) {
    int b = blockIdx.x, g = blockIdx.y;
    int c0 = g ? nch1 : 0;
    int nc = g ? nch2 : nch1;

    __shared__ unsigned char rl[CAPB];     // 3 KB   row-local per record
    __shared__ unsigned recs[CAPB];        // 12 KB  payload (load order)
    __shared__ unsigned outb[CAPB];        // 12 KB  row-sorted payload
    __shared__ int crow[BROWS], cur[BROWS], rstart[BROWS];
    __shared__ int total;
    int t = threadIdx.x, lane = t & 63, wid = t >> 6;
    if (t < BROWS) crow[t] = 0;
    if (t == 0) total = 0;
    __syncthreads();
    // phase A: pull this bucket's segment from each chunk
    for (int ci = t; ci < nc; ci += 512) {
        const int* ep = ends + (size_t)(c0 + ci) * NBUCK;
        int s = b ? ep[b - 1] : 0;
        int e = ep[b];
        int n = e - s;
        if (!n) continue;
        int dst = atomicAdd(&total, n);    // LDS int atomic, ~1/segment
        const uint2* src = inter + (size_t)(c0 + ci) * CHUNK + s;
        int k = 0;
        for (; k + 2 <= n; k += 2) {       // 2 loads in flight
            uint2 a  = src[k];
            uint2 b2 = src[k + 1];
            int p0 = dst + k, p1 = dst + k + 1;
            if (p0 < CAPB) { rl[p0] = (unsigned char)a.x;  recs[p0] = a.y;  atomicAdd(&crow[a.x], 1); }
            if (p1 < CAPB) { rl[p1] = (unsigned char)b2.x; recs[p1] = b2.y; atomicAdd(&crow[b2.x], 1); }
        }
        if (k < n) {
            uint2 a = src[k];
            int p0 = dst + k;
            if (p0 < CAPB) { rl[p0] = (unsigned char)a.x; recs[p0] = a.y; atomicAdd(&crow[a.x], 1); }
        }
    }
    __syncthreads();
    int cnt = min(total, CAPB);
    // wave 0: exclusive scan of 64 row counts
    if (wid == 0) {
        int v = crow[lane], s = v;
        #pragma unroll
        for (int d = 1; d < 64; d <<= 1) { int u = __shfl_up(s, d, 64); if (lane >= d) s += u; }
        cur[lane] = s - v;
        rstart[lane] = s - v;
    }
    __syncthreads();
    // rank-scatter into row-sorted order
    for (int i = t; i < cnt; i += 512) {
        int pos = atomicAdd(&cur[rl[i]], 1);
        outb[pos] = recs[i];
    }
    __syncthreads();                   // cur[r] is now end-of-row r
    // each wave register-accumulates 8 rows
    for (int r = wid * 8; r < wid * 8 + 8; ++r) {
        int grow = (b << BSHIFT) + r;
        if (grow >= N_NODES) break;
        int s0 = rstart[r], e0 = cur[r];
        float ax = 0.f, ay = 0.f;
        int j = s0;
        for (; j + 4 <= e0; j += 4) {
            unsigned c0r = outb[j];
            unsigned c1 = outb[j + 1];
            unsigned c2 = outb[j + 2];
            unsigned c3 = outb[j + 3];
            unsigned p0 = xb[(size_t)(c0r & 0xffffu) * 64 + lane];
            unsigned p1 = xb[(size_t)(c1 & 0xffffu) * 64 + lane];
            unsigned p2 = xb[(size_t)(c2 & 0xffffu) * 64 + lane];
            unsigned p3 = xb[(size_t)(c3 & 0xffffu) * 64 + lane];
            fma_rec(p0, c0r, ax, ay);
            fma_rec(p1, c1, ax, ay);
            fma_rec(p2, c2, ax, ay);
            fma_rec(p3, c3, ax, ay);
        }
        for (; j < e0; ++j) {
            unsigned c = outb[j];
            unsigned p = xb[(size_t)(c & 0xffffu) * 64 + lane];
            fma_rec(p, c, ax, ay);
        }
        vf2 rv; rv.x = ax; rv.y = ay;
        vf2* o = (vf2*)(out + (size_t)grow * OUT_STRIDE + g * D);
        __builtin_nontemporal_store(rv, o + lane);
    }
}

// ---------------- atomic scatter (fallback if ws too small) ----------------

__global__ void spmm_scatter(const float* __restrict__ x,
                             const int* __restrict__ ei,
                             const float* __restrict__ w,
                             float* __restrict__ out,
                             int E, int col_off) {
    long long gid = (long long)blockIdx.x * blockDim.x + threadIdx.x;
    int e    = (int)(gid >> 5);
    int lane = (int)(gid & 31);
    if (e >= E) return;
    int row  = ei[e];
    int col  = ei[E + e];
    float wv = w[e];
    const float4* xv = (const float4*)(x + (size_t)col * D);
    float4 v = xv[lane];
    float* o = out + (size_t)row * OUT_STRIDE + col_off + lane * 4;
    atomicAdd(o + 0, wv * v.x);
    atomicAdd(o + 1, wv * v.y);
    atomicAdd(o + 2, wv * v.z);
    atomicAdd(o + 3, wv * v.w);
}

extern "C" void kernel_launch(void* const* d_in, const int* in_sizes, int n_in,
                              void* d_out, int out_size, void* d_ws, size_t ws_size,
                              hipStream_t stream) {
    const float* x   = (const float*)d_in[0];
    const int*   ei1 = (const int*)d_in[1];
    const float* w1  = (const float*)d_in[2];
    const int*   ei2 = (const int*)d_in[3];
    const float* w2  = (const float*)d_in[4];
    float* out = (float*)d_out;

    const int E1 = in_sizes[1] / 2;   // 800000
    const int E2 = in_sizes[3] / 2;   // 1600000
    const int block = 256;

    int nch1 = (E1 + CHUNK - 1) / CHUNK;   // 98
    int nch2 = (E2 + CHUNK - 1) / CHUNK;   // 196
    int ncht = nch1 + nch2;                // 294

    // Workspace: ends (chunk-major) | inter (chunk-major) | xb
    size_t ends_b  = align256((size_t)ncht * NBUCK * sizeof(int));
    size_t inter_b = align256((size_t)ncht * CHUNK * sizeof(uint2));
    size_t xb_b    = align256((size_t)N_NODES * 64 * sizeof(unsigned));
    size_t o_ends  = 0;
    size_t o_int   = o_ends + ends_b;
    size_t o_xb    = o_int + inter_b;
    size_t needed  = o_xb + xb_b;

    // phase-A preload in bucket_accum assumes nc <= 512 (per-lane chunk pull)
    bool ok = (nch1 <= 512) && (nch2 <= 512);

    if (ws_size < needed || !ok) {
        // Fallback: atomic scatter (round-0).
        (void)hipMemsetAsync(d_out, 0, (size_t)out_size * sizeof(float), stream);
        long long th1 = (long long)E1 * 32;
        spmm_scatter<<<(int)((th1 + block - 1) / block), block, 0, stream>>>(
            x, ei1, w1, out, E1, 0);
        long long th2 = (long long)E2 * 32;
        spmm_scatter<<<(int)((th2 + block - 1) / block), block, 0, stream>>>(
            x, ei2, w2, out, E2, D);
        return;
    }

    char* ws = (char*)d_ws;
    int*      ends  = (int*)(ws + o_ends);
    uint2*    inter = (uint2*)(ws + o_int);
    unsigned* xb    = (unsigned*)(ws + o_xb);

    // 1. fused scatter + cvt (cvt blocks appended after scatter blocks)
    {
        int n4 = N_NODES * 32;                      // 1.6M float4 groups
        int ncvt = (n4 + 511) / 512;                // 3125
        prep<<<ncht + ncvt, 512, 0, stream>>>(
            ei1, w1, E1, nch1, ei2, w2, E2, ncht,
            inter, ends, x, (uint2*)xb, n4);
    }

    // 2. segment pull + in-LDS row sort + register accumulate
    {
        dim3 gr(NBUCK, 2);
        bucket_accum<<<gr, 512, 0, stream>>>(inter, ends, xb, out, nch1, nch2);
    }
}